// Round 18
// baseline (787.036 us; speedup 1.0000x reference)
//
#include <hip/hip_runtime.h>
#include <hip/hip_bf16.h>

// ---------- helpers ----------
__device__ __forceinline__ unsigned fmap(float f) {
    unsigned b = __float_as_uint(f);
    return (b & 0x80000000u) ? ~b : (b | 0x80000000u);
}
__device__ __forceinline__ float funmap(unsigned u) {
    unsigned b = (u & 0x80000000u) ? (u & 0x7FFFFFFFu) : ~u;
    return __uint_as_float(b);
}

// ---------- zero init (ws is poisoned 0xAA every call) ----------
__global__ void k_zero(unsigned* __restrict__ z, int nwords, unsigned* __restrict__ mm) {
    int i = blockIdx.x * blockDim.x + threadIdx.x;
    int stride = gridDim.x * blockDim.x;
    for (; i < nwords; i += stride) z[i] = 0u;
    if (blockIdx.x == 0 && threadIdx.x == 0) {
        mm[0] = 0u;          // running max (mapped), 0 == most negative
        mm[1] = 0xFFFFFFFFu; // running min (mapped)
    }
}

// ---------- detect keep_mask element width (uint8 vs int32) ----------
__global__ void k_maskdet(const unsigned char* __restrict__ m, int nbytes, int* __restrict__ flag) {
    __shared__ int s[256];
    int t = threadIdx.x;
    int cnt = 0;
    for (int i = t; i < nbytes; i += 256) cnt += (m[i] != 0);
    s[t] = cnt;
    __syncthreads();
    for (int d = 128; d > 0; d >>= 1) {
        if (t < d) s[t] += s[t + d];
        __syncthreads();
    }
    if (t == 0) flag[0] = (2 * s[0] > nbytes) ? 1 : 0;  // 1 = bytes, 0 = int32
}

// ---------- global min/max of edge_attr[:,1] ----------
__global__ void k_minmax(const float* __restrict__ attr, unsigned* __restrict__ mm, int E) {
    float lmin = 1e30f, lmax = -1e30f;
    for (int i = blockIdx.x * blockDim.x + threadIdx.x; i < E; i += gridDim.x * blockDim.x) {
        float w = attr[2 * i + 1];
        lmin = fminf(lmin, w);
        lmax = fmaxf(lmax, w);
    }
    #pragma unroll
    for (int o = 32; o > 0; o >>= 1) {
        lmin = fminf(lmin, __shfl_down(lmin, o));
        lmax = fmaxf(lmax, __shfl_down(lmax, o));
    }
    if ((threadIdx.x & 63) == 0) {
        atomicMax(mm + 0, fmap(lmax));
        atomicMin(mm + 1, fmap(lmin));
    }
}

// ---------- slot assignment: ONE atomic per edge (also builds histogram) ----------
__global__ void k_slot(const int* __restrict__ ei, int* __restrict__ cur,
                       int* __restrict__ rel, int E) {
    int i = blockIdx.x * blockDim.x + threadIdx.x;
    if (i >= E) return;
    int col = ei[E + i];
    rel[i] = atomicAdd(cur + col, 1);
}

// ---------- 3-kernel exclusive scan over cur (=cnt) ----------
__global__ __launch_bounds__(512) void k_scan_part(const int* __restrict__ in, int* __restrict__ out,
                                                   int* __restrict__ sums, int n) {
    __shared__ int s[512];
    int t = threadIdx.x;
    int i = blockIdx.x * 512 + t;
    int v = (i < n) ? in[i] : 0;
    s[t] = v;
    __syncthreads();
    for (int d = 1; d < 512; d <<= 1) {
        int x = (t >= d) ? s[t - d] : 0;
        __syncthreads();
        s[t] += x;
        __syncthreads();
    }
    if (i < n) out[i] = s[t] - v;
    if (t == 511) sums[blockIdx.x] = s[511];
}
__global__ __launch_bounds__(256) void k_scan_mid(int* __restrict__ sums, int n) {
    __shared__ int s[256];
    int t = threadIdx.x;
    int v = (t < n) ? sums[t] : 0;
    s[t] = v;
    __syncthreads();
    for (int d = 1; d < 256; d <<= 1) {
        int x = (t >= d) ? s[t - d] : 0;
        __syncthreads();
        s[t] += x;
        __syncthreads();
    }
    if (t < n) sums[t] = s[t] - v;
}
__global__ __launch_bounds__(512) void k_scan_add(int* __restrict__ out, const int* __restrict__ sums, int n) {
    int i = blockIdx.x * 512 + threadIdx.x;
    if (i < n) out[i] += sums[blockIdx.x];
}

// ---------- CSR scatter: NO atomics; ONE int2 store per edge ----------
// stored weight: keep ? v : -v  (v>=0). Layer1 weight = max(stored,0); layer2 = |stored|.
__global__ void k_scatter(const int* __restrict__ ei, const float* __restrict__ attr,
                          const unsigned char* __restrict__ maskb, const int* __restrict__ maski,
                          const int* __restrict__ mflag, const unsigned* __restrict__ mm,
                          const int* __restrict__ off, const int* __restrict__ rel,
                          int2* __restrict__ csr, int E) {
    int i = blockIdx.x * blockDim.x + threadIdx.x;
    if (i >= E) return;
    float wmax = funmap(mm[0]);
    float wmin = funmap(mm[1]);
    float w = attr[2 * i + 1];
    float v = (wmax - w) / (wmax - wmin);
    bool keep = mflag[0] ? (maskb[i] != 0) : (maski[i] != 0);
    float stored = keep ? v : -v;
    int col = ei[E + i];
    int p = off[col] + rel[i];
    csr[p] = make_int2(ei[i], __float_as_int(stored));
}

// ---------- degrees from CSR ranges (no atomics) -> dinv ----------
__global__ void k_deg(const int2* __restrict__ csr,
                      const int* __restrict__ off, const int* __restrict__ cnt,
                      float* __restrict__ dinv1, float* __restrict__ dinv2, int N) {
    int i = blockIdx.x * blockDim.x + threadIdx.x;
    if (i >= N) return;
    int s = off[i], c = cnt[i];
    float a = 0.0f, b = 0.0f;
    for (int j = 0; j < c; j++) {
        float v = __int_as_float(csr[s + j].y);
        a += fmaxf(v, 0.0f);
        b += fabsf(v);
    }
    dinv1[i] = 1.0f / sqrtf(a + 1.0f);
    dinv2[i] = 1.0f / sqrtf(b + 1.0f);
}

// ---------- tall-skinny GEMM with row-scale epilogue: Y[r] = (X@W)[r] * sc[r] ----------
__global__ __launch_bounds__(256) void k_gemm(const float* __restrict__ X, const float* __restrict__ W,
                                              float* __restrict__ Y, const float* __restrict__ sc, int n) {
    __shared__ float xs[64][68];
    __shared__ float ws[64 * 64];
    int t = threadIdx.x;
    int rowBase = blockIdx.x * 64;
    #pragma unroll
    for (int j = 0; j < 4; j++) {
        int f = t + 256 * j;
        reinterpret_cast<float4*>(ws)[f] = reinterpret_cast<const float4*>(W)[f];
    }
    #pragma unroll
    for (int j = 0; j < 4; j++) {
        int f = t + 256 * j;
        int r = f >> 4, c4 = (f & 15) << 2;
        float4 v = make_float4(0.f, 0.f, 0.f, 0.f);
        if (rowBase + r < n)
            v = *reinterpret_cast<const float4*>(X + (size_t)(rowBase + r) * 64 + c4);
        *reinterpret_cast<float4*>(&xs[r][c4]) = v;
    }
    __syncthreads();
    int c0 = (t & 15) << 2;
    int r0 = (t >> 4) << 2;
    float acc[4][4] = {};
    #pragma unroll
    for (int k0 = 0; k0 < 64; k0 += 4) {
        float4 xr[4], wv[4];
        #pragma unroll
        for (int rr = 0; rr < 4; rr++)
            xr[rr] = *reinterpret_cast<const float4*>(&xs[r0 + rr][k0]);
        #pragma unroll
        for (int kk = 0; kk < 4; kk++)
            wv[kk] = *reinterpret_cast<const float4*>(&ws[(k0 + kk) * 64 + c0]);
        #pragma unroll
        for (int rr = 0; rr < 4; rr++) {
            const float* xp = reinterpret_cast<const float*>(&xr[rr]);
            #pragma unroll
            for (int kk = 0; kk < 4; kk++) {
                const float a = xp[kk];
                const float* wp = reinterpret_cast<const float*>(&wv[kk]);
                #pragma unroll
                for (int cc = 0; cc < 4; cc++)
                    acc[rr][cc] = fmaf(a, wp[cc], acc[rr][cc]);
            }
        }
    }
    #pragma unroll
    for (int rr = 0; rr < 4; rr++) {
        int r = rowBase + r0 + rr;
        if (r < n) {
            float s = sc[r];
            float4 o = make_float4(acc[rr][0] * s, acc[rr][1] * s, acc[rr][2] * s, acc[rr][3] * s);
            *reinterpret_cast<float4*>(Y + (size_t)r * 64 + c0) = o;
        }
    }
}

// ---------- gather aggregation: one wave per node, 4 edges per iteration ----------
// lane = e*16 + q: e = edge-in-group (0..3), q = float4 chunk (0..15).
// Each lane loads csr[s+base+e] (broadcast within 16-lane group) and
// xw[r_e*64 + q*4 .. +3] as float4: one dwordx4 instruction covers 4 rows.
// After the loop, shfl_xor(16|32) folds the 4 edge groups; e==0 lanes do the
// float4 epilogue.
template <int LAYER>
__global__ __launch_bounds__(256) void k_gather(const float* __restrict__ xw, const float* __restrict__ dinv,
                                                const int* __restrict__ off, const int* __restrict__ cnt,
                                                const int2* __restrict__ csr,
                                                const float* __restrict__ bias, const float* __restrict__ xres,
                                                const int* __restrict__ batch, float* __restrict__ out,
                                                unsigned* __restrict__ seg, int N) {
    int wid = threadIdx.x >> 6;
    int lane = threadIdx.x & 63;
    int i = blockIdx.x * 4 + wid;
    if (i >= N) return;
    int s = off[i];
    int c = cnt[i];
    float di = dinv[i];
    int e = lane >> 4;   // edge slot in group of 4
    int q = lane & 15;   // float4 chunk of the row
    float4 acc = make_float4(0.f, 0.f, 0.f, 0.f);
    #pragma unroll 2
    for (int base = 0; base < c; base += 4) {
        int idx = base + e;
        int r = 0;
        float w = 0.0f;
        if (idx < c) {
            int2 ed = csr[s + idx];
            r = ed.x;
            float sv = __int_as_float(ed.y);
            w = (LAYER == 1) ? fmaxf(sv, 0.0f) : fabsf(sv);
        }
        float4 xv = *reinterpret_cast<const float4*>(xw + (size_t)r * 64 + (q << 2));
        acc.x = fmaf(w, xv.x, acc.x);
        acc.y = fmaf(w, xv.y, acc.y);
        acc.z = fmaf(w, xv.z, acc.z);
        acc.w = fmaf(w, xv.w, acc.w);
    }
    // fold the 4 edge groups (lanes q, q+16, q+32, q+48)
    acc.x += __shfl_xor(acc.x, 16); acc.y += __shfl_xor(acc.y, 16);
    acc.z += __shfl_xor(acc.z, 16); acc.w += __shfl_xor(acc.w, 16);
    acc.x += __shfl_xor(acc.x, 32); acc.y += __shfl_xor(acc.y, 32);
    acc.z += __shfl_xor(acc.z, 32); acc.w += __shfl_xor(acc.w, 32);
    if (e == 0) {
        float4 self = *reinterpret_cast<const float4*>(xw + (size_t)i * 64 + (q << 2));
        float4 b4   = *reinterpret_cast<const float4*>(bias + (q << 2));
        float4 v;
        v.x = fmaf(di, acc.x + self.x, b4.x);
        v.y = fmaf(di, acc.y + self.y, b4.y);
        v.z = fmaf(di, acc.z + self.z, b4.z);
        v.w = fmaf(di, acc.w + self.w, b4.w);
        if (LAYER == 1) {
            float4 o = make_float4(fmaxf(v.x, 0.f), fmaxf(v.y, 0.f), fmaxf(v.z, 0.f), fmaxf(v.w, 0.f));
            *reinterpret_cast<float4*>(out + (size_t)i * 64 + (q << 2)) = o;
        } else {
            float4 xr = *reinterpret_cast<const float4*>(xres + (size_t)i * 64 + (q << 2));
            int g = batch[i];
            unsigned* sp = seg + g * 64 + (q << 2);
            atomicMax(sp + 0, fmap(v.x + xr.x));
            atomicMax(sp + 1, fmap(v.y + xr.y));
            atomicMax(sp + 2, fmap(v.z + xr.z));
            atomicMax(sp + 3, fmap(v.w + xr.w));
        }
    }
}

// ---------- unmap segment-max result ----------
__global__ void k_out(const unsigned* __restrict__ seg, float* __restrict__ out, int n) {
    int i = blockIdx.x * blockDim.x + threadIdx.x;
    if (i < n) out[i] = funmap(seg[i]);
}

extern "C" void kernel_launch(void* const* d_in, const int* in_sizes, int n_in,
                              void* d_out, int out_size, void* d_ws, size_t ws_size,
                              hipStream_t stream) {
    const float* x             = (const float*)d_in[0];
    const int* ei              = (const int*)d_in[1];
    const float* attr          = (const float*)d_in[2];
    const int* batch           = (const int*)d_in[3];
    const unsigned char* maskb = (const unsigned char*)d_in[4];
    const int* maski           = (const int*)d_in[4];
    const float* W1            = (const float*)d_in[5];
    const float* b1            = (const float*)d_in[6];
    const float* W2            = (const float*)d_in[7];
    const float* b2            = (const float*)d_in[8];

    const int N = in_sizes[3];
    const int E = in_sizes[4];

    size_t cur_off = 0;
    auto alloc = [&](size_t bytes) -> char* {
        cur_off = (cur_off + 255) & ~(size_t)255;
        char* p = (char*)d_ws + cur_off;
        cur_off += bytes;
        return p;
    };
    int2* csr      = (int2*)alloc((size_t)E * 8);
    int* rel       = (int*)alloc((size_t)E * 4);
    // contiguous zero region: cur, seg
    int* curp      = (int*)alloc((size_t)N * 4);
    unsigned* seg  = (unsigned*)alloc((size_t)out_size * 4);
    char* zero_end = (char*)d_ws + cur_off;
    unsigned* mm   = (unsigned*)alloc(2 * 4);
    int* mflag     = (int*)alloc(4);
    int* offa      = (int*)alloc((size_t)N * 4);
    int* sums      = (int*)alloc(256 * 4);
    float* dinv1   = (float*)alloc((size_t)N * 4);
    float* dinv2   = (float*)alloc((size_t)N * 4);
    float* xw      = (float*)alloc((size_t)N * 64 * 4);
    float* x1      = (float*)alloc((size_t)N * 64 * 4);

    int zwords = (int)((zero_end - (char*)curp) / 4);

    const int B = 256;
    int nblkE = (E + B - 1) / B;
    int nblkN = (N + B - 1) / B;
    int nblkScan = (N + 511) / 512;
    int nblkGemm = (N + 63) / 64;
    int nblkGather = (N + 3) / 4;
    int detBytes = (E < 65536) ? E : 65536;

    k_zero<<<128, B, 0, stream>>>((unsigned*)curp, zwords, mm);
    k_maskdet<<<1, 256, 0, stream>>>(maskb, detBytes, mflag);
    k_minmax<<<512, B, 0, stream>>>(attr, mm, E);
    k_slot<<<nblkE, B, 0, stream>>>(ei, curp, rel, E);
    k_scan_part<<<nblkScan, 512, 0, stream>>>(curp, offa, sums, N);
    k_scan_mid<<<1, 256, 0, stream>>>(sums, nblkScan);
    k_scan_add<<<nblkScan, 512, 0, stream>>>(offa, sums, N);
    k_scatter<<<nblkE, B, 0, stream>>>(ei, attr, maskb, maski, mflag, mm, offa, rel, csr, E);
    k_deg<<<nblkN, B, 0, stream>>>(csr, offa, curp, dinv1, dinv2, N);

    // layer 1: xw = (x @ W1) * dinv1[row] ; x1 = relu(di*(gather + self) + b1)
    k_gemm<<<nblkGemm, B, 0, stream>>>(x, W1, xw, dinv1, N);
    k_gather<1><<<nblkGather, B, 0, stream>>>(xw, dinv1, offa, curp, csr, b1,
                                              nullptr, batch, x1, nullptr, N);
    // layer 2: xw = (x1 @ W2) * dinv2[row] ; v = di*(gather + self) + b2 + x ; segmax
    k_gemm<<<nblkGemm, B, 0, stream>>>(x1, W2, xw, dinv2, N);
    k_gather<2><<<nblkGather, B, 0, stream>>>(xw, dinv2, offa, curp, csr, b2,
                                              x, batch, nullptr, seg, N);
    k_out<<<(out_size + B - 1) / B, B, 0, stream>>>(seg, (float*)d_out, out_size);
}

// Round 19
// 486.036 us; speedup vs baseline: 1.6193x; 1.6193x over previous
//
#include <hip/hip_runtime.h>
#include <hip/hip_bf16.h>

// ---------- helpers ----------
__device__ __forceinline__ unsigned fmap(float f) {
    unsigned b = __float_as_uint(f);
    return (b & 0x80000000u) ? ~b : (b | 0x80000000u);
}
__device__ __forceinline__ float funmap(unsigned u) {
    unsigned b = (u & 0x80000000u) ? (u & 0x7FFFFFFFu) : ~u;
    return __uint_as_float(b);
}

// ---------- zero init (ws is poisoned 0xAA every call) ----------
__global__ void k_zero(unsigned* __restrict__ z, int nwords, unsigned* __restrict__ mm) {
    int i = blockIdx.x * blockDim.x + threadIdx.x;
    int stride = gridDim.x * blockDim.x;
    for (; i < nwords; i += stride) z[i] = 0u;
    if (blockIdx.x == 0 && threadIdx.x == 0) {
        mm[0] = 0u;          // running max (mapped), 0 == most negative
        mm[1] = 0xFFFFFFFFu; // running min (mapped)
    }
}

// ---------- detect keep_mask element width (uint8 vs int32) ----------
__global__ void k_maskdet(const unsigned char* __restrict__ m, int nbytes, int* __restrict__ flag) {
    __shared__ int s[256];
    int t = threadIdx.x;
    int cnt = 0;
    for (int i = t; i < nbytes; i += 256) cnt += (m[i] != 0);
    s[t] = cnt;
    __syncthreads();
    for (int d = 128; d > 0; d >>= 1) {
        if (t < d) s[t] += s[t + d];
        __syncthreads();
    }
    if (t == 0) flag[0] = (2 * s[0] > nbytes) ? 1 : 0;  // 1 = bytes, 0 = int32
}

// ---------- global min/max of edge_attr[:,1] ----------
__global__ void k_minmax(const float* __restrict__ attr, unsigned* __restrict__ mm, int E) {
    float lmin = 1e30f, lmax = -1e30f;
    for (int i = blockIdx.x * blockDim.x + threadIdx.x; i < E; i += gridDim.x * blockDim.x) {
        float w = attr[2 * i + 1];
        lmin = fminf(lmin, w);
        lmax = fmaxf(lmax, w);
    }
    #pragma unroll
    for (int o = 32; o > 0; o >>= 1) {
        lmin = fminf(lmin, __shfl_down(lmin, o));
        lmax = fmaxf(lmax, __shfl_down(lmax, o));
    }
    if ((threadIdx.x & 63) == 0) {
        atomicMax(mm + 0, fmap(lmax));
        atomicMin(mm + 1, fmap(lmin));
    }
}

// ---------- slot assignment: ONE atomic per edge (also builds histogram) ----------
__global__ void k_slot(const int* __restrict__ ei, int* __restrict__ cur,
                       int* __restrict__ rel, int E) {
    int i = blockIdx.x * blockDim.x + threadIdx.x;
    if (i >= E) return;
    int col = ei[E + i];
    rel[i] = atomicAdd(cur + col, 1);
}

// ---------- 3-kernel exclusive scan over cur (=cnt) ----------
__global__ __launch_bounds__(512) void k_scan_part(const int* __restrict__ in, int* __restrict__ out,
                                                   int* __restrict__ sums, int n) {
    __shared__ int s[512];
    int t = threadIdx.x;
    int i = blockIdx.x * 512 + t;
    int v = (i < n) ? in[i] : 0;
    s[t] = v;
    __syncthreads();
    for (int d = 1; d < 512; d <<= 1) {
        int x = (t >= d) ? s[t - d] : 0;
        __syncthreads();
        s[t] += x;
        __syncthreads();
    }
    if (i < n) out[i] = s[t] - v;
    if (t == 511) sums[blockIdx.x] = s[511];
}
__global__ __launch_bounds__(256) void k_scan_mid(int* __restrict__ sums, int n) {
    __shared__ int s[256];
    int t = threadIdx.x;
    int v = (t < n) ? sums[t] : 0;
    s[t] = v;
    __syncthreads();
    for (int d = 1; d < 256; d <<= 1) {
        int x = (t >= d) ? s[t - d] : 0;
        __syncthreads();
        s[t] += x;
        __syncthreads();
    }
    if (t < n) sums[t] = s[t] - v;
}
__global__ __launch_bounds__(512) void k_scan_add(int* __restrict__ out, const int* __restrict__ sums, int n) {
    int i = blockIdx.x * 512 + threadIdx.x;
    if (i < n) out[i] += sums[blockIdx.x];
}

// ---------- CSR scatter: NO atomics; ONE int2 store per edge ----------
// stored weight: keep ? v : -v  (v>=0). Layer1 weight = max(stored,0); layer2 = |stored|.
__global__ void k_scatter(const int* __restrict__ ei, const float* __restrict__ attr,
                          const unsigned char* __restrict__ maskb, const int* __restrict__ maski,
                          const int* __restrict__ mflag, const unsigned* __restrict__ mm,
                          const int* __restrict__ off, const int* __restrict__ rel,
                          int2* __restrict__ csr, int E) {
    int i = blockIdx.x * blockDim.x + threadIdx.x;
    if (i >= E) return;
    float wmax = funmap(mm[0]);
    float wmin = funmap(mm[1]);
    float w = attr[2 * i + 1];
    float v = (wmax - w) / (wmax - wmin);
    bool keep = mflag[0] ? (maskb[i] != 0) : (maski[i] != 0);
    float stored = keep ? v : -v;
    int col = ei[E + i];
    int p = off[col] + rel[i];
    csr[p] = make_int2(ei[i], __float_as_int(stored));
}

// ---------- degrees from CSR ranges (no atomics) -> dinv ----------
__global__ void k_deg(const int2* __restrict__ csr,
                      const int* __restrict__ off, const int* __restrict__ cnt,
                      float* __restrict__ dinv1, float* __restrict__ dinv2, int N) {
    int i = blockIdx.x * blockDim.x + threadIdx.x;
    if (i >= N) return;
    int s = off[i], c = cnt[i];
    float a = 0.0f, b = 0.0f;
    for (int j = 0; j < c; j++) {
        float v = __int_as_float(csr[s + j].y);
        a += fmaxf(v, 0.0f);
        b += fabsf(v);
    }
    dinv1[i] = 1.0f / sqrtf(a + 1.0f);
    dinv2[i] = 1.0f / sqrtf(b + 1.0f);
}

// ---------- tall-skinny GEMM with row-scale epilogue: Y[r] = (X@W)[r] * sc[r] ----------
__global__ __launch_bounds__(256) void k_gemm(const float* __restrict__ X, const float* __restrict__ W,
                                              float* __restrict__ Y, const float* __restrict__ sc, int n) {
    __shared__ float xs[64][68];
    __shared__ float ws[64 * 64];
    int t = threadIdx.x;
    int rowBase = blockIdx.x * 64;
    #pragma unroll
    for (int j = 0; j < 4; j++) {
        int f = t + 256 * j;
        reinterpret_cast<float4*>(ws)[f] = reinterpret_cast<const float4*>(W)[f];
    }
    #pragma unroll
    for (int j = 0; j < 4; j++) {
        int f = t + 256 * j;
        int r = f >> 4, c4 = (f & 15) << 2;
        float4 v = make_float4(0.f, 0.f, 0.f, 0.f);
        if (rowBase + r < n)
            v = *reinterpret_cast<const float4*>(X + (size_t)(rowBase + r) * 64 + c4);
        *reinterpret_cast<float4*>(&xs[r][c4]) = v;
    }
    __syncthreads();
    int c0 = (t & 15) << 2;
    int r0 = (t >> 4) << 2;
    float acc[4][4] = {};
    #pragma unroll
    for (int k0 = 0; k0 < 64; k0 += 4) {
        float4 xr[4], wv[4];
        #pragma unroll
        for (int rr = 0; rr < 4; rr++)
            xr[rr] = *reinterpret_cast<const float4*>(&xs[r0 + rr][k0]);
        #pragma unroll
        for (int kk = 0; kk < 4; kk++)
            wv[kk] = *reinterpret_cast<const float4*>(&ws[(k0 + kk) * 64 + c0]);
        #pragma unroll
        for (int rr = 0; rr < 4; rr++) {
            const float* xp = reinterpret_cast<const float*>(&xr[rr]);
            #pragma unroll
            for (int kk = 0; kk < 4; kk++) {
                const float a = xp[kk];
                const float* wp = reinterpret_cast<const float*>(&wv[kk]);
                #pragma unroll
                for (int cc = 0; cc < 4; cc++)
                    acc[rr][cc] = fmaf(a, wp[cc], acc[rr][cc]);
            }
        }
    }
    #pragma unroll
    for (int rr = 0; rr < 4; rr++) {
        int r = rowBase + r0 + rr;
        if (r < n) {
            float s = sc[r];
            float4 o = make_float4(acc[rr][0] * s, acc[rr][1] * s, acc[rr][2] * s, acc[rr][3] * s);
            *reinterpret_cast<float4*>(Y + (size_t)r * 64 + c0) = o;
        }
    }
}

// ---------- gather aggregation: one wave per node ----------
// Batch-load 64 csr entries per lane (ONE pointer-chase per 64 edges), then
// inner loop does 4 edges/step: (r,w) via __shfl (register dep only) and a
// float4 row load — 4 loads in flight x 4 rows each = 16 rows outstanding.
// lane = e*16 + q (e: edge slot 0..3, q: float4 chunk 0..15).
// After xor-fold, redistribute so every lane holds its scalar element and run
// the full-wave scalar epilogue (validated write pattern).
template <int LAYER>
__global__ __launch_bounds__(256) void k_gather(const float* __restrict__ xw, const float* __restrict__ dinv,
                                                const int* __restrict__ off, const int* __restrict__ cnt,
                                                const int2* __restrict__ csr,
                                                const float* __restrict__ bias, const float* __restrict__ xres,
                                                const int* __restrict__ batch, float* __restrict__ out,
                                                unsigned* __restrict__ seg, int N) {
    int wid = threadIdx.x >> 6;
    int lane = threadIdx.x & 63;
    int i = blockIdx.x * 4 + wid;
    if (i >= N) return;
    int s = off[i];
    int c = cnt[i];
    float di = dinv[i];
    int e = lane >> 4;   // edge slot in group of 4
    int q = lane & 15;   // float4 chunk of the row
    float4 acc = make_float4(0.f, 0.f, 0.f, 0.f);
    for (int base = 0; base < c; base += 64) {
        int m = min(64, c - base);
        int r = 0;
        float w = 0.0f;
        if (lane < m) {
            int2 ed = csr[s + base + lane];
            r = ed.x;
            float sv = __int_as_float(ed.y);
            w = (LAYER == 1) ? fmaxf(sv, 0.0f) : fabsf(sv);
        }
        #pragma unroll 4
        for (int ii = 0; ii < m; ii += 4) {
            int rj = __shfl(r, ii + e);      // register-only dep: loads pipeline
            float wj = __shfl(w, ii + e);
            float4 xv = *reinterpret_cast<const float4*>(xw + (size_t)rj * 64 + (q << 2));
            acc.x = fmaf(wj, xv.x, acc.x);
            acc.y = fmaf(wj, xv.y, acc.y);
            acc.z = fmaf(wj, xv.z, acc.z);
            acc.w = fmaf(wj, xv.w, acc.w);
        }
    }
    // fold the 4 edge groups (lanes q, q+16, q+32, q+48) -> all lanes hold chunk q sum
    acc.x += __shfl_xor(acc.x, 16); acc.y += __shfl_xor(acc.y, 16);
    acc.z += __shfl_xor(acc.z, 16); acc.w += __shfl_xor(acc.w, 16);
    acc.x += __shfl_xor(acc.x, 32); acc.y += __shfl_xor(acc.y, 32);
    acc.z += __shfl_xor(acc.z, 32); acc.w += __shfl_xor(acc.w, 32);
    // redistribute: lane l needs chunk (l>>2), component (l&3)
    int srcl = lane >> 2;
    float v0 = __shfl(acc.x, srcl);
    float v1 = __shfl(acc.y, srcl);
    float v2 = __shfl(acc.z, srcl);
    float v3 = __shfl(acc.w, srcl);
    int comp = lane & 3;
    float a = (comp == 0) ? v0 : (comp == 1) ? v1 : (comp == 2) ? v2 : v3;
    // full-wave scalar epilogue (validated write pattern)
    float self = xw[(size_t)i * 64 + lane];
    float v = fmaf(di, a + self, bias[lane]);
    if (LAYER == 1) {
        out[(size_t)i * 64 + lane] = fmaxf(v, 0.0f);
    } else {
        v += xres[(size_t)i * 64 + lane];
        int g = batch[i];
        atomicMax(seg + g * 64 + lane, fmap(v));
    }
}

// ---------- unmap segment-max result ----------
__global__ void k_out(const unsigned* __restrict__ seg, float* __restrict__ out, int n) {
    int i = blockIdx.x * blockDim.x + threadIdx.x;
    if (i < n) out[i] = funmap(seg[i]);
}

extern "C" void kernel_launch(void* const* d_in, const int* in_sizes, int n_in,
                              void* d_out, int out_size, void* d_ws, size_t ws_size,
                              hipStream_t stream) {
    const float* x             = (const float*)d_in[0];
    const int* ei              = (const int*)d_in[1];
    const float* attr          = (const float*)d_in[2];
    const int* batch           = (const int*)d_in[3];
    const unsigned char* maskb = (const unsigned char*)d_in[4];
    const int* maski           = (const int*)d_in[4];
    const float* W1            = (const float*)d_in[5];
    const float* b1            = (const float*)d_in[6];
    const float* W2            = (const float*)d_in[7];
    const float* b2            = (const float*)d_in[8];

    const int N = in_sizes[3];
    const int E = in_sizes[4];

    size_t cur_off = 0;
    auto alloc = [&](size_t bytes) -> char* {
        cur_off = (cur_off + 255) & ~(size_t)255;
        char* p = (char*)d_ws + cur_off;
        cur_off += bytes;
        return p;
    };
    int2* csr      = (int2*)alloc((size_t)E * 8);
    int* rel       = (int*)alloc((size_t)E * 4);
    // contiguous zero region: cur, seg
    int* curp      = (int*)alloc((size_t)N * 4);
    unsigned* seg  = (unsigned*)alloc((size_t)out_size * 4);
    char* zero_end = (char*)d_ws + cur_off;
    unsigned* mm   = (unsigned*)alloc(2 * 4);
    int* mflag     = (int*)alloc(4);
    int* offa      = (int*)alloc((size_t)N * 4);
    int* sums      = (int*)alloc(256 * 4);
    float* dinv1   = (float*)alloc((size_t)N * 4);
    float* dinv2   = (float*)alloc((size_t)N * 4);
    float* xw      = (float*)alloc((size_t)N * 64 * 4);
    float* x1      = (float*)alloc((size_t)N * 64 * 4);

    int zwords = (int)((zero_end - (char*)curp) / 4);

    const int B = 256;
    int nblkE = (E + B - 1) / B;
    int nblkN = (N + B - 1) / B;
    int nblkScan = (N + 511) / 512;
    int nblkGemm = (N + 63) / 64;
    int nblkGather = (N + 3) / 4;
    int detBytes = (E < 65536) ? E : 65536;

    k_zero<<<128, B, 0, stream>>>((unsigned*)curp, zwords, mm);
    k_maskdet<<<1, 256, 0, stream>>>(maskb, detBytes, mflag);
    k_minmax<<<512, B, 0, stream>>>(attr, mm, E);
    k_slot<<<nblkE, B, 0, stream>>>(ei, curp, rel, E);
    k_scan_part<<<nblkScan, 512, 0, stream>>>(curp, offa, sums, N);
    k_scan_mid<<<1, 256, 0, stream>>>(sums, nblkScan);
    k_scan_add<<<nblkScan, 512, 0, stream>>>(offa, sums, N);
    k_scatter<<<nblkE, B, 0, stream>>>(ei, attr, maskb, maski, mflag, mm, offa, rel, csr, E);
    k_deg<<<nblkN, B, 0, stream>>>(csr, offa, curp, dinv1, dinv2, N);

    // layer 1: xw = (x @ W1) * dinv1[row] ; x1 = relu(di*(gather + self) + b1)
    k_gemm<<<nblkGemm, B, 0, stream>>>(x, W1, xw, dinv1, N);
    k_gather<1><<<nblkGather, B, 0, stream>>>(xw, dinv1, offa, curp, csr, b1,
                                              nullptr, batch, x1, nullptr, N);
    // layer 2: xw = (x1 @ W2) * dinv2[row] ; v = di*(gather + self) + b2 + x ; segmax
    k_gemm<<<nblkGemm, B, 0, stream>>>(x1, W2, xw, dinv2, N);
    k_gather<2><<<nblkGather, B, 0, stream>>>(xw, dinv2, offa, curp, csr, b2,
                                              x, batch, nullptr, seg, N);
    k_out<<<(out_size + B - 1) / B, B, 0, stream>>>(seg, (float*)d_out, out_size);
}